// Round 5
// baseline (877.376 us; speedup 1.0000x reference)
//
#include <hip/hip_runtime.h>
#include <hip/hip_cooperative_groups.h>
#include <math.h>
#include <float.h>

namespace cg = cooperative_groups;

// Problem constants (fixed by the reference):
constexpr int N = 262144;   // tokens
constexpr int B = 4096;     // segments
constexpr int D = 256;      // relation_embed_dim
constexpr int A = 128;      // attention_dim

constexpr int CHUNK  = 1024;       // queries elements per scan block
constexpr int NCHUNK = N / CHUNK;  // 256
constexpr int SEGB   = 8;          // segments per block-unit in V phase
constexpr int GRID   = 1024;       // persistent blocks (4/CU, guaranteed by coop launch)

// native clang vector type (works with __builtin_nontemporal_load)
typedef float fvec4 __attribute__((ext_vector_type(4)));

// Single cooperative kernel: all 5 phases with grid-wide barriers between.
// __launch_bounds__(256,4): 4 waves/EU -> 4 blocks/CU -> 1024 blocks co-resident.
__global__ void __launch_bounds__(256, 4)
k_fused(const float* __restrict__ X, const int* __restrict__ q,
        const float* __restrict__ Wq, const float* __restrict__ Wk,
        int* __restrict__ seg, int* __restrict__ ends,
        int* __restrict__ partials, float* __restrict__ M,
        float* __restrict__ V, float* __restrict__ logits,
        float* __restrict__ out) {
    cg::grid_group grid = cg::this_grid();
    int t = threadIdx.x;
    int lane = t & 63, w = t >> 6;
    int bid = blockIdx.x;

    // ---- Phase A: blocks [0,256) chunk sums of queries; [256,512) M rows ----
    if (bid < NCHUNK) {
        int4 v = ((const int4*)q)[bid * (CHUNK / 4) + t];
        int s = v.x + v.y + v.z + v.w;
#pragma unroll
        for (int o = 32; o > 0; o >>= 1) s += __shfl_xor(s, o, 64);
        __shared__ int ws_[4];
        if (lane == 0) ws_[w] = s;
        __syncthreads();
        if (t == 0) partials[bid] = ws_[0] + ws_[1] + ws_[2] + ws_[3];
    } else if (bid < NCHUNK + D) {
        int d1 = bid - NCHUNK;   // 0..255
        int d2 = t;              // 0..255
        float acc = 0.f;
#pragma unroll 4
        for (int a = 0; a < A; a++) {
            acc = fmaf(Wk[a * D + d1], Wq[a * D + d2], acc);
        }
        M[d1 * D + d2] = acc;    // M = Wk^T Wq
    }
    grid.sync();

    // ---- Phase B: per-token segment id + segment end indices (blocks [0,256)) ----
    if (bid < NCHUNK) {
        int p = partials[t];
        int4 v = ((const int4*)q)[bid * (CHUNK / 4) + t];
        int tsum = v.x + v.y + v.z + v.w;
        int ps = p, ts = tsum;
#pragma unroll
        for (int o = 1; o < 64; o <<= 1) {
            int po = __shfl_up(ps, o, 64);
            int to = __shfl_up(ts, o, 64);
            if (lane >= o) { ps += po; ts += to; }
        }
        __shared__ int wp[4], wt[4];
        __shared__ int offs_sm;
        if (lane == 63) { wp[w] = ps; wt[w] = ts; }
        __syncthreads();
        int addp = 0, addt = 0;
#pragma unroll
        for (int i = 0; i < 4; i++) {
            if (i < w) { addp += wp[i]; addt += wt[i]; }
        }
        int sp_incl = ps + addp;
        int sm_incl = ts + addt;
        if (bid > 0 && t == bid - 1) offs_sm = sp_incl;
        if (bid == 0 && t == 0) offs_sm = 0;
        __syncthreads();
        int run = offs_sm + sm_incl - tsum;
        int base_idx = bid * CHUNK + t * 4;
        int qq[4] = {v.x, v.y, v.z, v.w};
#pragma unroll
        for (int k = 0; k < 4; k++) {
            int idx = base_idx + k;
            seg[idx] = run;
            if (qq[k]) { ends[run] = idx; run++; }
        }
    }
    grid.sync();

    // ---- Phase C: V[b] = M * x_{end_b}, 8 segments per block-unit (blocks [0,512)) ----
    if (bid < B / SEGB) {
        int b0 = bid * SEGB;
        const float4* xr[SEGB];
#pragma unroll
        for (int r = 0; r < SEGB; r++) {
            xr[r] = (const float4*)(X + (size_t)ends[b0 + r] * D);
        }
        const float4* Mrow = (const float4*)(M + t * D);
        float acc[SEGB];
#pragma unroll
        for (int r = 0; r < SEGB; r++) acc[r] = 0.f;
#pragma unroll 4
        for (int j = 0; j < D / 4; j++) {
            float4 m4 = Mrow[j];
#pragma unroll
            for (int r = 0; r < SEGB; r++) {
                float4 x4 = xr[r][j];
                acc[r] = fmaf(m4.x, x4.x, fmaf(m4.y, x4.y,
                         fmaf(m4.z, x4.z, fmaf(m4.w, x4.w, acc[r]))));
            }
        }
#pragma unroll
        for (int r = 0; r < SEGB; r++) V[(size_t)(b0 + r) * D + t] = acc[r];
    }
    grid.sync();

    // ---- Phase D: logits[i] = x_i . V[seg[i]], grid-stride, wave per 2 tokens ----
    for (int u = bid; u < N / 8; u += GRID) {
        int tok0 = (u * 4 + w) * 2;
        const fvec4* xa_p = (const fvec4*)(X + (size_t)tok0 * D) + lane;
        const fvec4* xb_p = (const fvec4*)(X + (size_t)(tok0 + 1) * D) + lane;
        fvec4 xa = __builtin_nontemporal_load(xa_p);
        fvec4 xb = __builtin_nontemporal_load(xb_p);
        int sa = seg[tok0];
        int sb = seg[tok0 + 1];
        float4 va = ((const float4*)(V + (size_t)sa * D))[lane];
        float4 vb = ((const float4*)(V + (size_t)sb * D))[lane];
        float pa = fmaf(xa.x, va.x, fmaf(xa.y, va.y, fmaf(xa.z, va.z, xa.w * va.w)));
        float pb = fmaf(xb.x, vb.x, fmaf(xb.y, vb.y, fmaf(xb.z, vb.z, xb.w * vb.w)));
#pragma unroll
        for (int o = 32; o > 0; o >>= 1) {
            pa += __shfl_xor(pa, o, 64);
            pb += __shfl_xor(pb, o, 64);
        }
        if (lane == 0) {
            *((float2*)(logits + tok0)) = make_float2(pa, pb);
        }
    }
    grid.sync();

    // ---- Phase E: per-segment online softmax, one wave per segment ----
    {
        int b = bid * 4 + w;   // GRID*4 == B exactly
        int start = (b == 0) ? 0 : (ends[b - 1] + 1);
        int end = ends[b];
        float m = -FLT_MAX, s = 0.f;
        for (int i = start + lane; i <= end; i += 64) {
            float x = logits[i];
            float nm = fmaxf(m, x);
            s = s * __expf(m - nm) + __expf(x - nm);
            m = nm;
        }
#pragma unroll
        for (int o = 32; o > 0; o >>= 1) {
            float mo = __shfl_xor(m, o, 64);
            float so = __shfl_xor(s, o, 64);
            float nm = fmaxf(m, mo);
            s = s * __expf(m - nm) + so * __expf(mo - nm);
            m = nm;
        }
        float r = 1.f / s;
        for (int i = start + lane; i <= end; i += 64) out[i] = __expf(logits[i] - m) * r;
    }
}

extern "C" void kernel_launch(void* const* d_in, const int* in_sizes, int n_in,
                              void* d_out, int out_size, void* d_ws, size_t ws_size,
                              hipStream_t stream) {
    const float* X  = (const float*)d_in[0];  // relation_embeds [N, D]
    const int*   q  = (const int*)d_in[1];    // queries [N]
    const float* Wq = (const float*)d_in[3];  // [A, D]
    const float* Wk = (const float*)d_in[4];  // [A, D]
    float* out = (float*)d_out;               // [N]

    char* ws = (char*)d_ws;
    size_t off = 0;
    auto alloc = [&](size_t bytes) -> char* {
        char* p = ws + off;
        off += (bytes + 255) & ~(size_t)255;
        return p;
    };
    int*   seg      = (int*)alloc((size_t)N * 4);
    int*   ends     = (int*)alloc((size_t)B * 4);
    int*   partials = (int*)alloc((size_t)NCHUNK * 4);
    float* M        = (float*)alloc((size_t)D * D * 4);
    float* V        = (float*)alloc((size_t)B * D * 4);
    float* logits   = (float*)alloc((size_t)N * 4);

    void* args[] = {(void*)&X, (void*)&q, (void*)&Wq, (void*)&Wk,
                    (void*)&seg, (void*)&ends, (void*)&partials,
                    (void*)&M, (void*)&V, (void*)&logits, (void*)&out};
    hipLaunchCooperativeKernel((const void*)k_fused, dim3(GRID), dim3(256),
                               args, 0, stream);
}

// Round 6
// 427.056 us; speedup vs baseline: 2.0545x; 2.0545x over previous
//
#include <hip/hip_runtime.h>
#include <math.h>
#include <float.h>

// Problem constants (fixed by the reference):
constexpr int N = 262144;   // tokens
constexpr int B = 4096;     // segments
constexpr int D = 256;      // relation_embed_dim
constexpr int A = 128;      // attention_dim

constexpr int CHUNK  = 1024;       // queries elements per scan block
constexpr int NCHUNK = N / CHUNK;  // 256
constexpr int SEGB   = 8;          // segments per block in compute_V
constexpr int SCAP   = 8192;       // LDS logits capacity per segment block (32 KB)

// native clang vector type (works with __builtin_nontemporal_load)
typedef float fvec4 __attribute__((ext_vector_type(4)));

// ---------- kernel 1: blocks [0,256) chunk sums of queries; blocks [256,512) M rows ----------
// M = Wk^T Wq  (D x D), M[d1][d2] = sum_a Wk[a][d1] * Wq[a][d2]
__global__ void k_partials_M(const int* __restrict__ q, int* __restrict__ partials,
                             const float* __restrict__ Wq, const float* __restrict__ Wk,
                             float* __restrict__ M) {
    int t = threadIdx.x;
    if (blockIdx.x < NCHUNK) {
        int4 v = ((const int4*)q)[blockIdx.x * (CHUNK / 4) + t];
        int s = v.x + v.y + v.z + v.w;
        int lane = t & 63, w = t >> 6;
#pragma unroll
        for (int o = 32; o > 0; o >>= 1) s += __shfl_xor(s, o, 64);
        __shared__ int ws_[4];
        if (lane == 0) ws_[w] = s;
        __syncthreads();
        if (t == 0) partials[blockIdx.x] = ws_[0] + ws_[1] + ws_[2] + ws_[3];
    } else {
        int d1 = blockIdx.x - NCHUNK;  // 0..255
        int d2 = t;                    // 0..255
        float acc = 0.f;
#pragma unroll 4
        for (int a = 0; a < A; a++) {
            acc = fmaf(Wk[a * D + d1], Wq[a * D + d2], acc);
        }
        M[d1 * D + d2] = acc;
    }
}

// ---------- kernel 2: segment end indices (seg[] no longer needed) ----------
__global__ void k_ends(const int* __restrict__ q, const int* __restrict__ partials,
                       int* __restrict__ ends) {
    int t = threadIdx.x;
    int lane = t & 63, w = t >> 6;
    int bid = blockIdx.x;
    int p = partials[t];
    int4 v = ((const int4*)q)[bid * (CHUNK / 4) + t];
    int tsum = v.x + v.y + v.z + v.w;
    int ps = p, ts = tsum;
#pragma unroll
    for (int o = 1; o < 64; o <<= 1) {
        int po = __shfl_up(ps, o, 64);
        int to = __shfl_up(ts, o, 64);
        if (lane >= o) { ps += po; ts += to; }
    }
    __shared__ int wp[4], wt[4];
    __shared__ int offs_sm;
    if (lane == 63) { wp[w] = ps; wt[w] = ts; }
    __syncthreads();
    int addp = 0, addt = 0;
#pragma unroll
    for (int i = 0; i < 4; i++) {
        if (i < w) { addp += wp[i]; addt += wt[i]; }
    }
    int sp_incl = ps + addp;
    int sm_incl = ts + addt;
    if (bid > 0 && t == bid - 1) offs_sm = sp_incl;
    if (bid == 0 && t == 0) offs_sm = 0;
    __syncthreads();
    int run = offs_sm + sm_incl - tsum;
    int base_idx = bid * CHUNK + t * 4;
    int qq[4] = {v.x, v.y, v.z, v.w};
#pragma unroll
    for (int k = 0; k < 4; k++) {
        if (qq[k]) { ends[run] = base_idx + k; run++; }
    }
}

// ---------- kernel 3: V[b] = M * x_{end_b}  (B x D), 8 segments per block ----------
__global__ void k_compute_V(const float* __restrict__ X, const int* __restrict__ ends,
                            const float* __restrict__ M, float* __restrict__ V) {
    int t = threadIdx.x;          // output dim d1
    int b0 = blockIdx.x * SEGB;
    const float4* xr[SEGB];
#pragma unroll
    for (int r = 0; r < SEGB; r++) {
        xr[r] = (const float4*)(X + (size_t)ends[b0 + r] * D);
    }
    const float4* Mrow = (const float4*)(M + t * D);
    float acc[SEGB];
#pragma unroll
    for (int r = 0; r < SEGB; r++) acc[r] = 0.f;
#pragma unroll 4
    for (int j = 0; j < D / 4; j++) {
        float4 m4 = Mrow[j];
#pragma unroll
        for (int r = 0; r < SEGB; r++) {
            float4 x4 = xr[r][j];
            acc[r] = fmaf(m4.x, x4.x, fmaf(m4.y, x4.y,
                     fmaf(m4.z, x4.z, fmaf(m4.w, x4.w, acc[r]))));
        }
    }
#pragma unroll
    for (int r = 0; r < SEGB; r++) V[(size_t)(b0 + r) * D + t] = acc[r];
}

// ---------- kernel 4: fused per-segment logits + softmax ----------
// Block b owns tokens [start, end]. Logits staged in LDS (no global round-trip),
// V[b] loaded once per wave, X rows streamed nontemporally (contiguous, coalesced).
__global__ void __launch_bounds__(256, 4)
k_seg_attn(const float* __restrict__ X, const int* __restrict__ ends,
           const float* __restrict__ V, float* __restrict__ out) {
    int b = blockIdx.x;
    int t = threadIdx.x;
    int lane = t & 63, w = t >> 6;
    int start = (b == 0) ? 0 : (ends[b - 1] + 1);
    int end = ends[b];
    int len = end - start + 1;
    float4 v4 = ((const float4*)(V + (size_t)b * D))[lane];
    __shared__ float sl[SCAP];
    __shared__ float wm[4], ws_[4];

    if (len <= SCAP) {
        // pass 1: logits into LDS, 2 tokens per wave-iteration (4 waves cover 8/iter)
        for (int i = start + 2 * w; i <= end; i += 8) {
            const fvec4* xp = (const fvec4*)(X + (size_t)i * D) + lane;
            fvec4 xa = __builtin_nontemporal_load(xp);
            float pa = fmaf(xa.x, v4.x, fmaf(xa.y, v4.y, fmaf(xa.z, v4.z, xa.w * v4.w)));
            bool hasb = (i + 1 <= end);
            float pb = 0.f;
            if (hasb) {
                const fvec4* xp2 = (const fvec4*)(X + (size_t)(i + 1) * D) + lane;
                fvec4 xb = __builtin_nontemporal_load(xp2);
                pb = fmaf(xb.x, v4.x, fmaf(xb.y, v4.y, fmaf(xb.z, v4.z, xb.w * v4.w)));
            }
#pragma unroll
            for (int o = 32; o > 0; o >>= 1) {
                pa += __shfl_xor(pa, o, 64);
                pb += __shfl_xor(pb, o, 64);
            }
            if (lane == 0) {
                sl[i - start] = pa;
                if (hasb) sl[i + 1 - start] = pb;
            }
        }
        __syncthreads();
        // block softmax over sl[0..len)
        float m = -FLT_MAX, s = 0.f;
        for (int i = t; i < len; i += 256) {
            float x = sl[i];
            float nm = fmaxf(m, x);
            s = s * __expf(m - nm) + __expf(x - nm);
            m = nm;
        }
#pragma unroll
        for (int o = 32; o > 0; o >>= 1) {
            float mo = __shfl_xor(m, o, 64);
            float so = __shfl_xor(s, o, 64);
            float nm = fmaxf(m, mo);
            s = s * __expf(m - nm) + so * __expf(mo - nm);
            m = nm;
        }
        if (lane == 0) { wm[w] = m; ws_[w] = s; }
        __syncthreads();
        float M4 = fmaxf(fmaxf(wm[0], wm[1]), fmaxf(wm[2], wm[3]));
        float S4 = ws_[0] * __expf(wm[0] - M4) + ws_[1] * __expf(wm[1] - M4)
                 + ws_[2] * __expf(wm[2] - M4) + ws_[3] * __expf(wm[3] - M4);
        float r = 1.f / S4;
        for (int i = t; i < len; i += 256) {
            out[start + i] = __expf(sl[i] - M4) * r;
        }
    } else {
        // fallback (len > SCAP, not expected): two-pass recompute, wave per token
        float m = -FLT_MAX, s = 0.f;
        for (int i = start + w; i <= end; i += 4) {
            const float4* xp = (const float4*)(X + (size_t)i * D) + lane;
            float4 xa = *xp;
            float p = fmaf(xa.x, v4.x, fmaf(xa.y, v4.y, fmaf(xa.z, v4.z, xa.w * v4.w)));
#pragma unroll
            for (int o = 32; o > 0; o >>= 1) p += __shfl_xor(p, o, 64);
            float nm = fmaxf(m, p);
            s = s * __expf(m - nm) + __expf(p - nm);
            m = nm;
        }
        if (lane == 0) { wm[w] = m; ws_[w] = s; }
        __syncthreads();
        float M4 = fmaxf(fmaxf(wm[0], wm[1]), fmaxf(wm[2], wm[3]));
        float S4 = ws_[0] * __expf(wm[0] - M4) + ws_[1] * __expf(wm[1] - M4)
                 + ws_[2] * __expf(wm[2] - M4) + ws_[3] * __expf(wm[3] - M4);
        float r = 1.f / S4;
        for (int i = start + w; i <= end; i += 4) {
            const float4* xp = (const float4*)(X + (size_t)i * D) + lane;
            float4 xa = *xp;
            float p = fmaf(xa.x, v4.x, fmaf(xa.y, v4.y, fmaf(xa.z, v4.z, xa.w * v4.w)));
#pragma unroll
            for (int o = 32; o > 0; o >>= 1) p += __shfl_xor(p, o, 64);
            if (lane == 0) out[i] = __expf(p - M4) * r;
        }
    }
}

extern "C" void kernel_launch(void* const* d_in, const int* in_sizes, int n_in,
                              void* d_out, int out_size, void* d_ws, size_t ws_size,
                              hipStream_t stream) {
    const float* X  = (const float*)d_in[0];  // relation_embeds [N, D]
    const int*   q  = (const int*)d_in[1];    // queries [N]
    const float* Wq = (const float*)d_in[3];  // [A, D]
    const float* Wk = (const float*)d_in[4];  // [A, D]
    float* out = (float*)d_out;               // [N]

    char* ws = (char*)d_ws;
    size_t off = 0;
    auto alloc = [&](size_t bytes) -> char* {
        char* p = ws + off;
        off += (bytes + 255) & ~(size_t)255;
        return p;
    };
    int*   ends     = (int*)alloc((size_t)B * 4);
    int*   partials = (int*)alloc((size_t)NCHUNK * 4);
    float* M        = (float*)alloc((size_t)D * D * 4);
    float* V        = (float*)alloc((size_t)B * D * 4);

    k_partials_M<<<NCHUNK + D, 256, 0, stream>>>(q, partials, Wq, Wk, M);
    k_ends<<<NCHUNK, 256, 0, stream>>>(q, partials, ends);
    k_compute_V<<<B / SEGB, 256, 0, stream>>>(X, ends, M, V);
    k_seg_attn<<<B, 256, 0, stream>>>(X, ends, V, out);
}

// Round 7
// 410.488 us; speedup vs baseline: 2.1374x; 1.0404x over previous
//
#include <hip/hip_runtime.h>
#include <math.h>
#include <float.h>

// Problem constants (fixed by the reference):
constexpr int N = 262144;   // tokens
constexpr int B = 4096;     // segments
constexpr int D = 256;      // relation_embed_dim
constexpr int A = 128;      // attention_dim

constexpr int CHUNK  = 1024;       // queries elements per scan block
constexpr int NCHUNK = N / CHUNK;  // 256
constexpr int SEGB   = 8;          // segments per block in compute_V
constexpr int GRIDL  = 4096;       // k_logits grid (4 blocks/CU co-resident)

// native clang vector type (works with __builtin_nontemporal_load/store)
typedef float fvec4 __attribute__((ext_vector_type(4)));

// ---------- kernel 1: blocks [0,256) chunk sums of queries; blocks [256,512) M rows ----------
// M = Wk^T Wq  (D x D), M[d1][d2] = sum_a Wk[a][d1] * Wq[a][d2]
__global__ void k_partials_M(const int* __restrict__ q, int* __restrict__ partials,
                             const float* __restrict__ Wq, const float* __restrict__ Wk,
                             float* __restrict__ M) {
    int t = threadIdx.x;
    if (blockIdx.x < NCHUNK) {
        int4 v = ((const int4*)q)[blockIdx.x * (CHUNK / 4) + t];
        int s = v.x + v.y + v.z + v.w;
        int lane = t & 63, w = t >> 6;
#pragma unroll
        for (int o = 32; o > 0; o >>= 1) s += __shfl_xor(s, o, 64);
        __shared__ int ws_[4];
        if (lane == 0) ws_[w] = s;
        __syncthreads();
        if (t == 0) partials[blockIdx.x] = ws_[0] + ws_[1] + ws_[2] + ws_[3];
    } else {
        int d1 = blockIdx.x - NCHUNK;  // 0..255
        int d2 = t;                    // 0..255
        float acc = 0.f;
#pragma unroll 4
        for (int a = 0; a < A; a++) {
            acc = fmaf(Wk[a * D + d1], Wq[a * D + d2], acc);
        }
        M[d1 * D + d2] = acc;
    }
}

// ---------- kernel 2: per-token segment id + segment end indices ----------
__global__ void k_seg_ends(const int* __restrict__ q, const int* __restrict__ partials,
                           int* __restrict__ seg, int* __restrict__ ends) {
    int t = threadIdx.x;
    int lane = t & 63, w = t >> 6;
    int bid = blockIdx.x;
    int p = partials[t];
    int4 v = ((const int4*)q)[bid * (CHUNK / 4) + t];
    int tsum = v.x + v.y + v.z + v.w;
    int ps = p, ts = tsum;
#pragma unroll
    for (int o = 1; o < 64; o <<= 1) {
        int po = __shfl_up(ps, o, 64);
        int to = __shfl_up(ts, o, 64);
        if (lane >= o) { ps += po; ts += to; }
    }
    __shared__ int wp[4], wt[4];
    __shared__ int offs_sm;
    if (lane == 63) { wp[w] = ps; wt[w] = ts; }
    __syncthreads();
    int addp = 0, addt = 0;
#pragma unroll
    for (int i = 0; i < 4; i++) {
        if (i < w) { addp += wp[i]; addt += wt[i]; }
    }
    int sp_incl = ps + addp;
    int sm_incl = ts + addt;
    if (bid > 0 && t == bid - 1) offs_sm = sp_incl;
    if (bid == 0 && t == 0) offs_sm = 0;
    __syncthreads();
    int run = offs_sm + sm_incl - tsum;
    int base_idx = bid * CHUNK + t * 4;
    int qq[4] = {v.x, v.y, v.z, v.w};
#pragma unroll
    for (int k = 0; k < 4; k++) {
        int idx = base_idx + k;
        seg[idx] = run;
        if (qq[k]) { ends[run] = idx; run++; }
    }
}

// ---------- kernel 3: V[b] = M * x_{end_b}  (B x D), 8 segments per block ----------
__global__ void k_compute_V(const float* __restrict__ X, const int* __restrict__ ends,
                            const float* __restrict__ M, float* __restrict__ V) {
    int t = threadIdx.x;          // output dim d1
    int b0 = blockIdx.x * SEGB;
    const float4* xr[SEGB];
#pragma unroll
    for (int r = 0; r < SEGB; r++) {
        xr[r] = (const float4*)(X + (size_t)ends[b0 + r] * D);
    }
    const float4* Mrow = (const float4*)(M + t * D);
    float acc[SEGB];
#pragma unroll
    for (int r = 0; r < SEGB; r++) acc[r] = 0.f;
#pragma unroll 4
    for (int j = 0; j < D / 4; j++) {
        float4 m4 = Mrow[j];
#pragma unroll
        for (int r = 0; r < SEGB; r++) {
            float4 x4 = xr[r][j];
            acc[r] = fmaf(m4.x, x4.x, fmaf(m4.y, x4.y,
                     fmaf(m4.z, x4.z, fmaf(m4.w, x4.w, acc[r]))));
        }
    }
#pragma unroll
    for (int r = 0; r < SEGB; r++) V[(size_t)(b0 + r) * D + t] = acc[r];
}

// ---------- kernel 4: logits[i] = x_i . V[seg[i]] ----------
// Grid-stride (4096 blocks, 4/CU): each wave handles 4 tokens/iter, 4 iters total.
// 8 x 16B loads in flight per lane; nontemporal X (streaming) keeps V L2-hot.
__global__ void __launch_bounds__(256, 4)
k_logits(const float* __restrict__ X, const int* __restrict__ seg,
         const float* __restrict__ V, float* __restrict__ logits) {
    int w = threadIdx.x >> 6;     // 0..3
    int lane = threadIdx.x & 63;
    // unit = one wave-iteration = 4 tokens; total units = N/4
    for (int u = blockIdx.x * 4 + w; u < N / 4; u += GRIDL * 4) {
        int tok0 = u * 4;
        float p[4];
#pragma unroll
        for (int k = 0; k < 4; k++) {
            const fvec4* xp = (const fvec4*)(X + (size_t)(tok0 + k) * D) + lane;
            fvec4 x4 = __builtin_nontemporal_load(xp);
            int s = seg[tok0 + k];
            float4 v4 = ((const float4*)(V + (size_t)s * D))[lane];
            p[k] = fmaf(x4.x, v4.x, fmaf(x4.y, v4.y, fmaf(x4.z, v4.z, x4.w * v4.w)));
        }
#pragma unroll
        for (int o = 32; o > 0; o >>= 1) {
#pragma unroll
            for (int k = 0; k < 4; k++) p[k] += __shfl_xor(p[k], o, 64);
        }
        if (lane == 0) {
            fvec4 r = {p[0], p[1], p[2], p[3]};
            __builtin_nontemporal_store(r, (fvec4*)(logits + tok0));
        }
    }
}

// ---------- kernel 5: per-segment online softmax: one wave per segment ----------
__global__ void k_softmax(const float* __restrict__ logits, const int* __restrict__ ends,
                          float* __restrict__ out) {
    int w = threadIdx.x >> 6;
    int lane = threadIdx.x & 63;
    int b = blockIdx.x * 4 + w;
    int start = (b == 0) ? 0 : (ends[b - 1] + 1);
    int end = ends[b];
    float m = -FLT_MAX, s = 0.f;
    for (int i = start + lane; i <= end; i += 64) {
        float x = logits[i];
        float nm = fmaxf(m, x);
        s = s * __expf(m - nm) + __expf(x - nm);
        m = nm;
    }
#pragma unroll
    for (int o = 32; o > 0; o >>= 1) {
        float mo = __shfl_xor(m, o, 64);
        float so = __shfl_xor(s, o, 64);
        float nm = fmaxf(m, mo);
        s = s * __expf(m - nm) + so * __expf(mo - nm);
        m = nm;
    }
    float r = 1.f / s;
    for (int i = start + lane; i <= end; i += 64) out[i] = __expf(logits[i] - m) * r;
}

extern "C" void kernel_launch(void* const* d_in, const int* in_sizes, int n_in,
                              void* d_out, int out_size, void* d_ws, size_t ws_size,
                              hipStream_t stream) {
    const float* X  = (const float*)d_in[0];  // relation_embeds [N, D]
    const int*   q  = (const int*)d_in[1];    // queries [N]
    const float* Wq = (const float*)d_in[3];  // [A, D]
    const float* Wk = (const float*)d_in[4];  // [A, D]
    float* out = (float*)d_out;               // [N]

    char* ws = (char*)d_ws;
    size_t off = 0;
    auto alloc = [&](size_t bytes) -> char* {
        char* p = ws + off;
        off += (bytes + 255) & ~(size_t)255;
        return p;
    };
    int*   seg      = (int*)alloc((size_t)N * 4);
    int*   ends     = (int*)alloc((size_t)B * 4);
    int*   partials = (int*)alloc((size_t)NCHUNK * 4);
    float* M        = (float*)alloc((size_t)D * D * 4);
    float* V        = (float*)alloc((size_t)B * D * 4);
    float* logits   = (float*)alloc((size_t)N * 4);

    k_partials_M<<<NCHUNK + D, 256, 0, stream>>>(q, partials, Wq, Wk, M);
    k_seg_ends<<<NCHUNK, 256, 0, stream>>>(q, partials, seg, ends);
    k_compute_V<<<B / SEGB, 256, 0, stream>>>(X, ends, M, V);
    k_logits<<<GRIDL, 256, 0, stream>>>(X, seg, V, logits);
    k_softmax<<<B / 4, 256, 0, stream>>>(logits, ends, out);
}

// Round 8
// 403.053 us; speedup vs baseline: 2.1768x; 1.0184x over previous
//
#include <hip/hip_runtime.h>
#include <math.h>
#include <float.h>

// Problem constants (fixed by the reference):
constexpr int N = 262144;   // tokens
constexpr int B = 4096;     // segments
constexpr int D = 256;      // relation_embed_dim
constexpr int A = 128;      // attention_dim

constexpr int CHUNK  = 1024;       // queries elements per scan block
constexpr int NCHUNK = N / CHUNK;  // 256
constexpr int SEGB   = 8;          // segments per block in compute_V

// native clang vector type (works with __builtin_nontemporal_load/store)
typedef float fvec4 __attribute__((ext_vector_type(4)));

// ---------- kernel 1: fused scan + seg/ends + M ----------
// Blocks [0,256): single-pass scan over queries chunks. Each block computes its
// chunk total, publishes (total+1) via device atomic into scan_ws (poison 0xAA
// is negative => "unpublished"); threads t<bid poll predecessor totals and
// accumulate the exclusive chunk offset in LDS. All 512 blocks co-resident
// (tiny resource footprint) so the spin is deadlock-free. Deterministic even
// across graph replays: same q => same published totals.
// Blocks [256,512): M = Wk^T Wq rows.
__global__ void k_scan_M(const int* __restrict__ q,
                         const float* __restrict__ Wq, const float* __restrict__ Wk,
                         float* __restrict__ M, int* __restrict__ seg,
                         int* __restrict__ ends, int* __restrict__ scan_ws) {
    int bid = blockIdx.x;
    int t = threadIdx.x;
    if (bid >= NCHUNK) {
        int d1 = bid - NCHUNK;   // 0..255
        int d2 = t;              // 0..255
        float acc = 0.f;
#pragma unroll 4
        for (int a = 0; a < A; a++) {
            acc = fmaf(Wk[a * D + d1], Wq[a * D + d2], acc);
        }
        M[d1 * D + d2] = acc;
        return;
    }
    int lane = t & 63, w = t >> 6;
    int4 v = ((const int4*)q)[bid * (CHUNK / 4) + t];
    int tsum = v.x + v.y + v.z + v.w;
    // inclusive shuffle scan of per-thread sums within each wave
    int ts = tsum;
#pragma unroll
    for (int o = 1; o < 64; o <<= 1) {
        int to = __shfl_up(ts, o, 64);
        if (lane >= o) ts += to;
    }
    __shared__ int wt[4];
    __shared__ int offs_sm;
    if (lane == 63) wt[w] = ts;
    if (t == 0) offs_sm = 0;
    __syncthreads();
    int addt = 0;
#pragma unroll
    for (int i = 0; i < 4; i++) {
        if (i < w) addt += wt[i];
    }
    int sm_incl = ts + addt;                       // inclusive scan within chunk
    int total = wt[0] + wt[1] + wt[2] + wt[3];     // chunk total
    // publish own total (tagged +1 so published values are >= 1; poison < 0)
    if (t == 0) atomicExch(&scan_ws[bid], total + 1);
    // poll predecessors: thread t handles chunk t (t < bid)
    if (t < bid) {
        int val;
        do {
            val = atomicAdd(&scan_ws[t], 0);       // device-scope atomic read
        } while (val < 1);
        atomicAdd(&offs_sm, val - 1);              // LDS accumulate
    }
    __syncthreads();
    int run = offs_sm + sm_incl - tsum;            // ones strictly before my first elem
    int base_idx = bid * CHUNK + t * 4;
    int qq[4] = {v.x, v.y, v.z, v.w};
#pragma unroll
    for (int k = 0; k < 4; k++) {
        int idx = base_idx + k;
        seg[idx] = run;
        if (qq[k]) { ends[run] = idx; run++; }
    }
}

// ---------- kernel 2: V[b] = M * x_{end_b}  (B x D), 8 segments per block ----------
__global__ void k_compute_V(const float* __restrict__ X, const int* __restrict__ ends,
                            const float* __restrict__ M, float* __restrict__ V) {
    int t = threadIdx.x;          // output dim d1
    int b0 = blockIdx.x * SEGB;
    const float4* xr[SEGB];
#pragma unroll
    for (int r = 0; r < SEGB; r++) {
        xr[r] = (const float4*)(X + (size_t)ends[b0 + r] * D);
    }
    const float4* Mrow = (const float4*)(M + t * D);
    float acc[SEGB];
#pragma unroll
    for (int r = 0; r < SEGB; r++) acc[r] = 0.f;
#pragma unroll 4
    for (int j = 0; j < D / 4; j++) {
        float4 m4 = Mrow[j];
#pragma unroll
        for (int r = 0; r < SEGB; r++) {
            float4 x4 = xr[r][j];
            acc[r] = fmaf(m4.x, x4.x, fmaf(m4.y, x4.y,
                     fmaf(m4.z, x4.z, fmaf(m4.w, x4.w, acc[r]))));
        }
    }
#pragma unroll
    for (int r = 0; r < SEGB; r++) V[(size_t)(b0 + r) * D + t] = acc[r];
}

// ---------- kernel 3: logits[i] = x_i . V[seg[i]] : one wave per 2 tokens ----------
// (exact R4-best structure: one-shot blocks, 2 tokens/wave, nontemporal X)
__global__ void k_logits(const float* __restrict__ X, const int* __restrict__ seg,
                         const float* __restrict__ V, float* __restrict__ logits) {
    int wave = threadIdx.x >> 6;  // 0..3
    int lane = threadIdx.x & 63;
    int tok0 = (blockIdx.x * 4 + wave) * 2;
    const fvec4* xa_p = (const fvec4*)(X + (size_t)tok0 * D) + lane;
    const fvec4* xb_p = (const fvec4*)(X + (size_t)(tok0 + 1) * D) + lane;
    fvec4 xa = __builtin_nontemporal_load(xa_p);
    fvec4 xb = __builtin_nontemporal_load(xb_p);
    int sa = seg[tok0];
    int sb = seg[tok0 + 1];
    float4 va = ((const float4*)(V + (size_t)sa * D))[lane];
    float4 vb = ((const float4*)(V + (size_t)sb * D))[lane];
    float pa = fmaf(xa.x, va.x, fmaf(xa.y, va.y, fmaf(xa.z, va.z, xa.w * va.w)));
    float pb = fmaf(xb.x, vb.x, fmaf(xb.y, vb.y, fmaf(xb.z, vb.z, xb.w * vb.w)));
#pragma unroll
    for (int o = 32; o > 0; o >>= 1) {
        pa += __shfl_xor(pa, o, 64);
        pb += __shfl_xor(pb, o, 64);
    }
    if (lane == 0) {
        *((float2*)(logits + tok0)) = make_float2(pa, pb);
    }
}

// ---------- kernel 4: per-segment online softmax: one wave per segment ----------
__global__ void k_softmax(const float* __restrict__ logits, const int* __restrict__ ends,
                          float* __restrict__ out) {
    int w = threadIdx.x >> 6;
    int lane = threadIdx.x & 63;
    int b = blockIdx.x * 4 + w;
    int start = (b == 0) ? 0 : (ends[b - 1] + 1);
    int end = ends[b];
    float m = -FLT_MAX, s = 0.f;
    for (int i = start + lane; i <= end; i += 64) {
        float x = logits[i];
        float nm = fmaxf(m, x);
        s = s * __expf(m - nm) + __expf(x - nm);
        m = nm;
    }
#pragma unroll
    for (int o = 32; o > 0; o >>= 1) {
        float mo = __shfl_xor(m, o, 64);
        float so = __shfl_xor(s, o, 64);
        float nm = fmaxf(m, mo);
        s = s * __expf(m - nm) + so * __expf(mo - nm);
        m = nm;
    }
    float r = 1.f / s;
    for (int i = start + lane; i <= end; i += 64) out[i] = __expf(logits[i] - m) * r;
}

extern "C" void kernel_launch(void* const* d_in, const int* in_sizes, int n_in,
                              void* d_out, int out_size, void* d_ws, size_t ws_size,
                              hipStream_t stream) {
    const float* X  = (const float*)d_in[0];  // relation_embeds [N, D]
    const int*   q  = (const int*)d_in[1];    // queries [N]
    const float* Wq = (const float*)d_in[3];  // [A, D]
    const float* Wk = (const float*)d_in[4];  // [A, D]
    float* out = (float*)d_out;               // [N]

    char* ws = (char*)d_ws;
    size_t off = 0;
    auto alloc = [&](size_t bytes) -> char* {
        char* p = ws + off;
        off += (bytes + 255) & ~(size_t)255;
        return p;
    };
    int*   seg      = (int*)alloc((size_t)N * 4);
    int*   ends     = (int*)alloc((size_t)B * 4);
    int*   scan_ws  = (int*)alloc((size_t)NCHUNK * 4);
    float* M        = (float*)alloc((size_t)D * D * 4);
    float* V        = (float*)alloc((size_t)B * D * 4);
    float* logits   = (float*)alloc((size_t)N * 4);

    k_scan_M<<<NCHUNK + D, 256, 0, stream>>>(q, Wq, Wk, M, seg, ends, scan_ws);
    k_compute_V<<<B / SEGB, 256, 0, stream>>>(X, ends, M, V);
    k_logits<<<N / 8, 256, 0, stream>>>(X, seg, V, logits);
    k_softmax<<<B / 4, 256, 0, stream>>>(logits, ends, out);
}